// Round 3
// baseline (1205.950 us; speedup 1.0000x reference)
//
#include <hip/hip_runtime.h>

#define BT 8192
#define T 200
#define OBSD 8
#define STD 16
#define CTD 4
#define HD 64
#define BB 16

// ws offsets (ushort elements)
#define O_WENC  0
#define O_WROLL 24576
#define O_WMLP0 49152
#define O_WMLP1 55296
#define O_WC0   56320
#define O_WC    62464
#define O_WCOUT 74752
#define O_WSYS  75776
#define WS_TOT  76288

typedef short s8v __attribute__((ext_vector_type(8)));
typedef float f4v __attribute__((ext_vector_type(4)));

#define MFMA(a,b,c) __builtin_amdgcn_mfma_f32_16x16x32_bf16((a),(b),(c),0,0,0)

__device__ __forceinline__ unsigned short f2b(float f){
  union{float f; unsigned u;} v; v.f=f;
  unsigned u=v.u;
  return (unsigned short)((u + 0x7FFFu + ((u>>16)&1u))>>16);
}
__device__ __forceinline__ float sigm(float x){ return 1.f/(1.f+__expf(-x)); }
__device__ __forceinline__ float tanh_(float x){ return 1.f - 2.f/(__expf(2.f*x)+1.f); }

__global__ void prep(const float* __restrict__ rWi, const float* __restrict__ rWh,
                     const float* __restrict__ cWi, const float* __restrict__ cWh,
                     const float* __restrict__ mW0, const float* __restrict__ mW1,
                     const float* __restrict__ mcW0, const float* __restrict__ mcW,
                     const float* __restrict__ mcWout,
                     const float* __restrict__ sysA, const float* __restrict__ sysB,
                     unsigned short* __restrict__ ws){
  int idx = blockIdx.x*256 + threadIdx.x;
  if (idx >= WS_TOT) return;
  float v = 0.f;
  int o = idx;
  if (o < 24576){            // WENC [256][96]: rz-combined | i_n | h_n ; K = [x(8)|h(64)|pad]
    int n=o/96, k=o%96;
    if (n<128){ if(k<8) v=rWi[n*8+k]; else if(k<72) v=rWh[n*64+(k-8)]; }
    else if (n<192){ int j=n-128; if(k<8) v=rWi[(128+j)*8+k]; }
    else { int j=n-192; if(k>=8&&k<72) v=rWh[(128+j)*64+(k-8)]; }
  } else if (o < 49152){     // WROLL [256][96]: K = [inpt(32)|h(64)]
    o-=24576; int n=o/96,k=o%96;
    if (n<128){ if(k<32) v=cWi[n*32+k]; else v=cWh[n*64+(k-32)]; }
    else if (n<192){ int j=n-128; if(k<32) v=cWi[(128+j)*32+k]; }
    else { int j=n-192; if(k>=32) v=cWh[(128+j)*64+(k-32)]; }
  } else if (o < 55296){     // WMLP0 [64][96]: K = [hT(64)|obs0(8)|pad]
    o-=49152; int n=o/96,k=o%96; if(k<72) v=mW0[n*72+k];
  } else if (o < 56320){     // WMLP1 [16][64]
    o-=55296; v=mW1[o];
  } else if (o < 62464){     // WC0 [64][96]: K = [hc(64)|obs(8)|err(8)|pad]
    o-=56320; int n=o/96,k=o%96; if(k<80) v=mcW0[n*80+k];
  } else if (o < 74752){     // WC [3][64][64]
    o-=62464; v=mcW[o];
  } else if (o < 75776){     // WCOUT [16][64] (rows 4..15 zero)
    o-=74752; int n=o/64,k=o%64; if(n<4) v=mcWout[n*64+k];
  } else {                   // WSYS [16][32]: [(A - I) | B | pad]
    o-=75776; int n=o/32,k=o%32;
    if(k<16) v=sysA[n*16+k] - (k==n?1.f:0.f);
    else if(k<20) v=sysB[n*4+(k-16)];
  }
  ws[idx] = f2b(v);
}

__launch_bounds__(256, 2)
__global__ void fused(const float* __restrict__ obs,
                      const float* __restrict__ sysC,
                      const float* __restrict__ ebi, const float* __restrict__ ebh,
                      const float* __restrict__ cbi, const float* __restrict__ cbh,
                      const float* __restrict__ mb0, const float* __restrict__ mb1,
                      const float* __restrict__ mcb0,
                      const float* __restrict__ lng, const float* __restrict__ lnb,
                      const float* __restrict__ mcb,
                      const float* __restrict__ mcbout,
                      const unsigned short* __restrict__ ws,
                      float* __restrict__ out)
{
  float* oh  = out;                                   // [B][200][8]
  float* cm  = out + (size_t)BT*T*OBSD;               // [B][199][4]
  float* stt = cm  + (size_t)BT*(T-1)*CTD;            // [B][200][16]

  __shared__ unsigned short sX[BB][104];   // GEMM A staging (bf16)
  __shared__ unsigned short sU[BB][104];   // control input u
  __shared__ unsigned short sXc[BB][72];   // per-layer activations (K=64)
  __shared__ unsigned short sXs[BB][40];   // [state|cmd] (K=32 pad)
  __shared__ float sH[BB][66];             // fp32 h / hc master
  __shared__ float sS[BB][18];             // fp32 state master
  __shared__ float sLN[BB][66];            // fp32 pre-LN
  __shared__ float sC[OBSD][STD];
  __shared__ float sBrz[128], sBin[64], sBhn[64];
  __shared__ float sBc0[64], sBcl[192], sLg[192], sLb[192], sBco[16];

  const int tid = threadIdx.x;
  const int wv = tid>>6, ln = tid&63;
  const int lr = ln&15, lk = ln>>4;
  const int r0 = blockIdx.x * BB;

  // ---- one-time init ----
  for (int p = tid; p < BB*104; p += 256){ int r=p/104, c=p%104; if (c>=8) sX[r][c]=0; }
  for (int p = tid; p < BB*104; p += 256){ int r=p/104, c=p%104; if (c>=80) sU[r][c]=0; }
  for (int p = tid; p < BB*72;  p += 256){ int r=p/72,  c=p%72;  if (c>=64) sXc[r][c]=0; }
  for (int p = tid; p < BB*40;  p += 256){ int r=p/40,  c=p%40;  if (c>=20) sXs[r][c]=0; }
  for (int p = tid; p < BB*64;  p += 256){ sH[p/64][p%64]=0.f; }
  if (tid < 128) sBrz[tid] = ebi[tid]+ebh[tid];
  if (tid < 64){ sBin[tid]=ebi[128+tid]; sBhn[tid]=ebh[128+tid]; }
  if (tid < 128) sC[tid/16][tid%16] = sysC[tid];
  if (tid < 64)  sBc0[tid]=mcb0[tid];
  if (tid < 192){ sBcl[tid]=mcb[tid]; sLg[tid]=lng[tid]; sLb[tid]=lnb[tid]; }
  if (tid < 16)  sBco[tid] = (tid<4)? mcbout[tid] : 0.f;

  // encoder weight fragments (held in VGPRs for the whole loop)
  s8v wE[4][3];
  #pragma unroll
  for (int g=0; g<4; ++g)
    #pragma unroll
    for (int kk=0; kk<3; ++kk)
      wE[g][kk] = *(const s8v*)(ws + O_WENC + (g*64 + wv*16 + lr)*96 + kk*32 + lk*8);

  const int orow = tid>>3, ocol = tid&7;   // staging thread map (tid<128)
  float ox = 0.f;
  if (tid < 128) ox = obs[(size_t)(r0+orow)*(T*OBSD) + ocol];
  __syncthreads();

  // ================= encoder: 200 GRU steps =================
  for (int t=0; t<T; ++t){
    if (tid < 128) sX[orow][ocol] = f2b(ox);
    __syncthreads();
    if (tid < 128 && t+1 < T) ox = obs[(size_t)(r0+orow)*(T*OBSD) + (t+1)*OBSD + ocol];
    s8v a[3];
    #pragma unroll
    for (int kk=0;kk<3;++kk) a[kk] = *(const s8v*)&sX[lr][kk*32 + lk*8];
    f4v acc[4];
    #pragma unroll
    for (int g=0; g<4; ++g){
      f4v c = {0.f,0.f,0.f,0.f};
      #pragma unroll
      for (int kk=0;kk<3;++kk) c = MFMA(a[kk], wE[g][kk], c);
      acc[g]=c;
    }
    __syncthreads();    // A-reads done before h writes
    int j = wv*16 + lr;
    #pragma unroll
    for (int ri=0; ri<4; ++ri){
      int row = lk*4 + ri;
      float rr = sigm(acc[0][ri] + sBrz[j]);
      float zz = sigm(acc[1][ri] + sBrz[64+j]);
      float nn = tanh_(acc[2][ri] + sBin[j] + rr*(acc[3][ri] + sBhn[j]));
      float hv = sH[row][j];
      hv = (1.f-zz)*nn + zz*hv;
      sH[row][j] = hv;
      sX[row][8+j] = f2b(hv);
    }
    __syncthreads();
  }

  // ================= initial-state MLP =================
  if (tid < 128){
    #pragma unroll
    for (int cc=0; cc<8; ++cc) sX[orow][ocol*8+cc] = f2b(sH[orow][ocol*8+cc]);
    sX[orow][64+ocol] = f2b(obs[(size_t)(r0+orow)*(T*OBSD) + ocol]);
  }
  __syncthreads();
  {
    s8v a[3], w0[3];
    #pragma unroll
    for (int kk=0;kk<3;++kk){
      a[kk]  = *(const s8v*)&sX[lr][kk*32+lk*8];
      w0[kk] = *(const s8v*)(ws + O_WMLP0 + (wv*16+lr)*96 + kk*32 + lk*8);
    }
    f4v c = {0.f,0.f,0.f,0.f};
    #pragma unroll
    for (int kk=0;kk<3;++kk) c = MFMA(a[kk], w0[kk], c);
    int col = wv*16+lr; float bb = mb0[col];
    #pragma unroll
    for (int ri=0;ri<4;++ri) sXc[lk*4+ri][col] = f2b(tanh_(c[ri]+bb));
  }
  __syncthreads();
  if (wv==0){
    s8v a[2], w1[2];
    #pragma unroll
    for (int kk=0;kk<2;++kk){
      a[kk]  = *(const s8v*)&sXc[lr][kk*32+lk*8];
      w1[kk] = *(const s8v*)(ws + O_WMLP1 + lr*64 + kk*32 + lk*8);
    }
    f4v c = {0.f,0.f,0.f,0.f};
    #pragma unroll
    for (int kk=0;kk<2;++kk) c = MFMA(a[kk], w1[kk], c);
    float bb = mb1[lr];
    #pragma unroll
    for (int ri=0;ri<4;++ri){
      int row = lk*4+ri;
      float s = c[ri]+bb;
      sS[row][lr] = s;
      stt[(size_t)(r0+row)*(T*STD) + lr] = s;
    }
  } else {
    for (int p = tid-64; p < BB*64; p += 192) sH[p/64][p%64] = 0.f;                 // hc = 0
    for (int p = tid-64; p < BB*64; p += 192){ int r=p/64,c=p%64; sX[r][32+c]=0; }  // hc bf16 = 0
  }
  if (tid<128) sBrz[tid] = cbi[tid]+cbh[tid];
  if (tid<64){ sBin[tid]=cbi[128+tid]; sBhn[tid]=cbh[128+tid]; }

  // rollout weight fragments
  s8v wR[4][3];
  #pragma unroll
  for (int g=0; g<4; ++g)
    #pragma unroll
    for (int kk=0; kk<3; ++kk)
      wR[g][kk] = *(const s8v*)(ws + O_WROLL + (g*64 + wv*16 + lr)*96 + kk*32 + lk*8);
  s8v wC0[3];
  #pragma unroll
  for (int kk=0;kk<3;++kk) wC0[kk] = *(const s8v*)(ws + O_WC0 + (wv*16+lr)*96 + kk*32 + lk*8);
  s8v wCl[3][2];
  #pragma unroll
  for (int i=0;i<3;++i)
    #pragma unroll
    for (int kk=0;kk<2;++kk)
      wCl[i][kk] = *(const s8v*)(ws + O_WC + i*4096 + (wv*16+lr)*64 + kk*32 + lk*8);
  s8v wCo[2], wSy;
  if (wv==0){
    #pragma unroll
    for (int kk=0;kk<2;++kk) wCo[kk] = *(const s8v*)(ws + O_WCOUT + lr*64 + kk*32 + lk*8);
    wSy = *(const s8v*)(ws + O_WSYS + lr*32 + lk*8);
  }

  float oxr = 0.f;
  if (tid<128) oxr = obs[(size_t)(r0+orow)*(T*OBSD) + OBSD + ocol];   // obs[:,1]
  __syncthreads();

  // ================= rollout: 199 steps =================
  for (int i=0; i<T-1; ++i){
    // --- A0: pred/err + staging ---
    if (tid < 128){
      float pr = 0.f;
      #pragma unroll
      for (int k=0;k<16;++k) pr += sS[orow][k]*sC[ocol][k];
      oh[(size_t)(r0+orow)*(T*OBSD) + i*OBSD + ocol] = pr;
      float er = oxr - pr;
      unsigned short ob = f2b(oxr), eb = f2b(er);
      sX[orow][16+ocol]=ob; sX[orow][24+ocol]=eb;
      sU[orow][64+ocol]=ob; sU[orow][72+ocol]=eb;
      float s1 = sS[orow][ocol], s2 = sS[orow][8+ocol];
      unsigned short b1v=f2b(s1), b2v=f2b(s2);
      sX[orow][ocol]=b1v;  sX[orow][8+ocol]=b2v;
      sXs[orow][ocol]=b1v; sXs[orow][8+ocol]=b2v;
    }
    __syncthreads();
    if (tid<128 && i+1 < T-1) oxr = obs[(size_t)(r0+orow)*(T*OBSD) + (i+2)*OBSD + ocol];

    // --- GRU GEMM ---
    {
      s8v a[3];
      #pragma unroll
      for (int kk=0;kk<3;++kk) a[kk] = *(const s8v*)&sX[lr][kk*32 + lk*8];
      f4v acc[4];
      #pragma unroll
      for (int g=0; g<4; ++g){
        f4v c = {0.f,0.f,0.f,0.f};
        #pragma unroll
        for (int kk=0;kk<3;++kk) c = MFMA(a[kk], wR[g][kk], c);
        acc[g]=c;
      }
      __syncthreads();
      int j = wv*16 + lr;
      #pragma unroll
      for (int ri=0; ri<4; ++ri){
        int row = lk*4 + ri;
        float rr = sigm(acc[0][ri] + sBrz[j]);
        float zz = sigm(acc[1][ri] + sBrz[64+j]);
        float nn = tanh_(acc[2][ri] + sBin[j] + rr*(acc[3][ri] + sBhn[j]));
        float hv = sH[row][j];
        hv = (1.f-zz)*nn + zz*hv;
        sH[row][j] = hv;
        unsigned short hb = f2b(hv);
        sX[row][32+j] = hb;
        sU[row][j] = hb;
      }
    }
    __syncthreads();

    // --- control L0 ---
    {
      s8v a2[3];
      #pragma unroll
      for (int kk=0;kk<3;++kk) a2[kk] = *(const s8v*)&sU[lr][kk*32+lk*8];
      f4v c = {0.f,0.f,0.f,0.f};
      #pragma unroll
      for (int kk=0;kk<3;++kk) c = MFMA(a2[kk], wC0[kk], c);
      int col = wv*16+lr; float bb = sBc0[col];
      #pragma unroll
      for (int ri=0;ri<4;++ri) sLN[lk*4+ri][col] = fmaxf(c[ri]+bb, 0.f);
    }
    __syncthreads();

    // --- 3 × (LN + layer) ---
    #pragma unroll
    for (int L=0; L<3; ++L){
      if (tid<128){
        float xv[8], sm=0.f, sq=0.f;
        #pragma unroll
        for (int cc=0;cc<8;++cc){ float x=sLN[orow][ocol*8+cc]; xv[cc]=x; sm+=x; sq+=x*x; }
        sm+=__shfl_xor(sm,1); sq+=__shfl_xor(sq,1);
        sm+=__shfl_xor(sm,2); sq+=__shfl_xor(sq,2);
        sm+=__shfl_xor(sm,4); sq+=__shfl_xor(sq,4);
        float mn = sm*0.015625f;
        float vr = sq*0.015625f - mn*mn;
        float scl = rsqrtf(vr + 1e-5f);
        #pragma unroll
        for (int cc=0;cc<8;++cc){ int c2=ocol*8+cc;
          sXc[orow][c2] = f2b((xv[cc]-mn)*scl*sLg[L*64+c2] + sLb[L*64+c2]); }
      }
      __syncthreads();
      s8v a2[2];
      #pragma unroll
      for (int kk=0;kk<2;++kk) a2[kk] = *(const s8v*)&sXc[lr][kk*32+lk*8];
      f4v c = {0.f,0.f,0.f,0.f};
      #pragma unroll
      for (int kk=0;kk<2;++kk) c = MFMA(a2[kk], wCl[L][kk], c);
      int col = wv*16+lr; float bb = sBcl[L*64+col];
      __syncthreads();   // reads of sXc/sLN complete before overwrite
      if (L<2){
        #pragma unroll
        for (int ri=0;ri<4;++ri) sLN[lk*4+ri][col] = fmaxf(c[ri]+bb, 0.f);
      } else {
        #pragma unroll
        for (int ri=0;ri<4;++ri) sXc[lk*4+ri][col] = f2b(fmaxf(c[ri]+bb, 0.f));
      }
      __syncthreads();
    }

    // --- cmd + state update (wave 0) ---
    if (wv==0){
      s8v a2[2];
      #pragma unroll
      for (int kk=0;kk<2;++kk) a2[kk] = *(const s8v*)&sXc[lr][kk*32+lk*8];
      f4v c = {0.f,0.f,0.f,0.f};
      #pragma unroll
      for (int kk=0;kk<2;++kk) c = MFMA(a2[kk], wCo[kk], c);
      if (lr < 4){
        float bb = sBco[lr];
        #pragma unroll
        for (int ri=0;ri<4;++ri){
          int row = lk*4+ri;
          float cv = c[ri]+bb;
          cm[(size_t)(r0+row)*((T-1)*CTD) + i*CTD + lr] = cv;
          sXs[row][16+lr] = f2b(cv);
        }
      }
      s8v as = *(const s8v*)&sXs[lr][lk*8];
      f4v d = {0.f,0.f,0.f,0.f};
      d = MFMA(as, wSy, d);
      #pragma unroll
      for (int ri=0;ri<4;++ri){
        int row = lk*4+ri;
        float ns = sS[row][lr] + d[ri];
        ns = (ns > -100.f && ns < 100.f) ? ns : 0.f;
        sS[row][lr] = ns;
        stt[(size_t)(r0+row)*(T*STD) + (i+1)*STD + lr] = ns;
      }
    }
    __syncthreads();
  }

  // final obs_hat[199]
  if (tid<128){
    float pr = 0.f;
    #pragma unroll
    for (int k=0;k<16;++k) pr += sS[orow][k]*sC[ocol][k];
    oh[(size_t)(r0+orow)*(T*OBSD) + (T-1)*OBSD + ocol] = pr;
  }
}

extern "C" void kernel_launch(void* const* d_in, const int* in_sizes, int n_in,
                              void* d_out, int out_size, void* d_ws, size_t ws_size,
                              hipStream_t stream){
  const float* obs    = (const float*)d_in[0];
  const float* sysA   = (const float*)d_in[1];
  const float* sysB   = (const float*)d_in[2];
  const float* sysC   = (const float*)d_in[3];
  const float* rWi    = (const float*)d_in[4];
  const float* rWh    = (const float*)d_in[5];
  const float* rbi    = (const float*)d_in[6];
  const float* rbh    = (const float*)d_in[7];
  const float* cWi    = (const float*)d_in[8];
  const float* cWh    = (const float*)d_in[9];
  const float* cbi    = (const float*)d_in[10];
  const float* cbh    = (const float*)d_in[11];
  const float* mW0    = (const float*)d_in[12];
  const float* mb0    = (const float*)d_in[13];
  const float* mW1    = (const float*)d_in[14];
  const float* mb1    = (const float*)d_in[15];
  const float* mcW0   = (const float*)d_in[16];
  const float* mcb0   = (const float*)d_in[17];
  const float* lng    = (const float*)d_in[18];
  const float* lnb    = (const float*)d_in[19];
  const float* mcW    = (const float*)d_in[20];
  const float* mcb    = (const float*)d_in[21];
  const float* mcWout = (const float*)d_in[22];
  const float* mcbout = (const float*)d_in[23];
  unsigned short* ws  = (unsigned short*)d_ws;

  prep<<<(WS_TOT+255)/256, 256, 0, stream>>>(rWi,rWh,cWi,cWh,mW0,mW1,mcW0,mcW,mcWout,sysA,sysB,ws);
  fused<<<BT/BB, 256, 0, stream>>>(obs,sysC,rbi,rbh,cbi,cbh,mb0,mb1,mcb0,lng,lnb,mcb,mcbout,ws,(float*)d_out);
}

// Round 8
// 1190.143 us; speedup vs baseline: 1.0133x; 1.0133x over previous
//
#include <hip/hip_runtime.h>

#define BT 8192
#define T 200
#define OBSD 8
#define STD 16
#define CTD 4
#define HD 64
#define BB 16

// ws offsets (ushort elements)
#define O_WENC  0
#define O_WROLL 24576
#define O_WMLP0 49152
#define O_WMLP1 55296
#define O_WC0   56320
#define O_WC    62464
#define O_WCOUT 74752
#define O_WSYS  75776
#define WS_TOT  76288

typedef short s8v __attribute__((ext_vector_type(8)));
typedef float f4v __attribute__((ext_vector_type(4)));

#define MFMA(a,b,c) __builtin_amdgcn_mfma_f32_16x16x32_bf16((a),(b),(c),0,0,0)

__device__ __forceinline__ unsigned short f2b(float f){
  union{float f; unsigned u;} v; v.f=f;
  unsigned u=v.u;
  return (unsigned short)((u + 0x7FFFu + ((u>>16)&1u))>>16);
}
__device__ __forceinline__ float sigm(float x){ return 1.f/(1.f+__expf(-x)); }
__device__ __forceinline__ float tanh_(float x){ return 1.f - 2.f/(__expf(2.f*x)+1.f); }

// LDS-only barrier: __syncthreads minus the vmcnt(0) drain.
// Global ops here are output stores (never re-read) and register prefetches
// (auto-waitcnt'd at use) — no LDS state depends on them, so values are
// identical to __syncthreads; only the store-drain stall is removed.
__device__ __forceinline__ void barrier_lds(){
  asm volatile("s_waitcnt lgkmcnt(0)" : : : "memory");
  __builtin_amdgcn_s_barrier();
  asm volatile("" : : : "memory");
}

__global__ void prep(const float* __restrict__ rWi, const float* __restrict__ rWh,
                     const float* __restrict__ cWi, const float* __restrict__ cWh,
                     const float* __restrict__ mW0, const float* __restrict__ mW1,
                     const float* __restrict__ mcW0, const float* __restrict__ mcW,
                     const float* __restrict__ mcWout,
                     const float* __restrict__ sysA, const float* __restrict__ sysB,
                     unsigned short* __restrict__ ws){
  int idx = blockIdx.x*256 + threadIdx.x;
  if (idx >= WS_TOT) return;
  float v = 0.f;
  int o = idx;
  if (o < 24576){            // WENC [256][96]: rz-combined | i_n | h_n ; K = [x(8)|h(64)|pad]
    int n=o/96, k=o%96;
    if (n<128){ if(k<8) v=rWi[n*8+k]; else if(k<72) v=rWh[n*64+(k-8)]; }
    else if (n<192){ int j=n-128; if(k<8) v=rWi[(128+j)*8+k]; }
    else { int j=n-192; if(k>=8&&k<72) v=rWh[(128+j)*64+(k-8)]; }
  } else if (o < 49152){     // WROLL [256][96]: K = [inpt(32)|h(64)]
    o-=24576; int n=o/96,k=o%96;
    if (n<128){ if(k<32) v=cWi[n*32+k]; else v=cWh[n*64+(k-32)]; }
    else if (n<192){ int j=n-128; if(k<32) v=cWi[(128+j)*32+k]; }
    else { int j=n-192; if(k>=32) v=cWh[(128+j)*64+(k-32)]; }
  } else if (o < 55296){     // WMLP0 [64][96]: K = [hT(64)|obs0(8)|pad]
    o-=49152; int n=o/96,k=o%96; if(k<72) v=mW0[n*72+k];
  } else if (o < 56320){     // WMLP1 [16][64]
    o-=55296; v=mW1[o];
  } else if (o < 62464){     // WC0 [64][96]: K = [hc(64)|obs(8)|err(8)|pad]
    o-=56320; int n=o/96,k=o%96; if(k<80) v=mcW0[n*80+k];
  } else if (o < 74752){     // WC [3][64][64]
    o-=62464; v=mcW[o];
  } else if (o < 75776){     // WCOUT [16][64] (rows 4..15 zero)
    o-=74752; int n=o/64,k=o%64; if(n<4) v=mcWout[n*64+k];
  } else {                   // WSYS [16][32]: [(A - I) | B | pad]
    o-=75776; int n=o/32,k=o%32;
    if(k<16) v=sysA[n*16+k] - (k==n?1.f:0.f);
    else if(k<20) v=sysB[n*4+(k-16)];
  }
  ws[idx] = f2b(v);
}

__launch_bounds__(256, 2)
__global__ void fused(const float* __restrict__ obs,
                      const float* __restrict__ sysC,
                      const float* __restrict__ ebi, const float* __restrict__ ebh,
                      const float* __restrict__ cbi, const float* __restrict__ cbh,
                      const float* __restrict__ mb0, const float* __restrict__ mb1,
                      const float* __restrict__ mcb0,
                      const float* __restrict__ lng, const float* __restrict__ lnb,
                      const float* __restrict__ mcb,
                      const float* __restrict__ mcbout,
                      const unsigned short* __restrict__ ws,
                      float* __restrict__ out)
{
  float* oh  = out;                                   // [B][200][8]
  float* cm  = out + (size_t)BT*T*OBSD;               // [B][199][4]
  float* stt = cm  + (size_t)BT*(T-1)*CTD;            // [B][200][16]

  __shared__ unsigned short sX[BB][104];   // GEMM A staging (bf16)
  __shared__ unsigned short sU[BB][104];   // control input u
  __shared__ unsigned short sXc[BB][72];   // per-layer activations (K=64)
  __shared__ unsigned short sXs[BB][40];   // [state|cmd] (K=32 pad)
  __shared__ float sH[BB][66];             // fp32 h / hc master
  __shared__ float sS[BB][18];             // fp32 state master
  __shared__ float sLN[BB][66];            // fp32 pre-LN
  __shared__ float sC[OBSD][STD];
  __shared__ float sBrz[128], sBin[64], sBhn[64];
  __shared__ float sBc0[64], sBcl[192], sLg[192], sLb[192], sBco[16];

  const int tid = threadIdx.x;
  const int wv = tid>>6, ln = tid&63;
  const int lr = ln&15, lk = ln>>4;
  const int r0 = blockIdx.x * BB;

  // ---- one-time init ----
  for (int p = tid; p < BB*104; p += 256){ int r=p/104, c=p%104; if (c>=8) sX[r][c]=0; }
  for (int p = tid; p < BB*104; p += 256){ int r=p/104, c=p%104; if (c>=80) sU[r][c]=0; }
  for (int p = tid; p < BB*72;  p += 256){ int r=p/72,  c=p%72;  if (c>=64) sXc[r][c]=0; }
  for (int p = tid; p < BB*40;  p += 256){ int r=p/40,  c=p%40;  if (c>=20) sXs[r][c]=0; }
  for (int p = tid; p < BB*64;  p += 256){ sH[p/64][p%64]=0.f; }
  if (tid < 128) sBrz[tid] = ebi[tid]+ebh[tid];
  if (tid < 64){ sBin[tid]=ebi[128+tid]; sBhn[tid]=ebh[128+tid]; }
  if (tid < 128) sC[tid/16][tid%16] = sysC[tid];
  if (tid < 64)  sBc0[tid]=mcb0[tid];
  if (tid < 192){ sBcl[tid]=mcb[tid]; sLg[tid]=lng[tid]; sLb[tid]=lnb[tid]; }
  if (tid < 16)  sBco[tid] = (tid<4)? mcbout[tid] : 0.f;

  // encoder weight fragments (held in VGPRs for the whole loop)
  s8v wE[4][3];
  #pragma unroll
  for (int g=0; g<4; ++g)
    #pragma unroll
    for (int kk=0; kk<3; ++kk)
      wE[g][kk] = *(const s8v*)(ws + O_WENC + (g*64 + wv*16 + lr)*96 + kk*32 + lk*8);

  const int orow = tid>>3, ocol = tid&7;   // staging thread map (tid<128)
  float ox = 0.f;
  if (tid < 128) ox = obs[(size_t)(r0+orow)*(T*OBSD) + ocol];
  barrier_lds();

  // ================= encoder: 200 GRU steps =================
  for (int t=0; t<T; ++t){
    if (tid < 128) sX[orow][ocol] = f2b(ox);
    barrier_lds();
    if (tid < 128 && t+1 < T) ox = obs[(size_t)(r0+orow)*(T*OBSD) + (t+1)*OBSD + ocol];
    s8v a[3];
    #pragma unroll
    for (int kk=0;kk<3;++kk) a[kk] = *(const s8v*)&sX[lr][kk*32 + lk*8];
    f4v acc[4];
    #pragma unroll
    for (int g=0; g<4; ++g){
      f4v c = {0.f,0.f,0.f,0.f};
      #pragma unroll
      for (int kk=0;kk<3;++kk) c = MFMA(a[kk], wE[g][kk], c);
      acc[g]=c;
    }
    barrier_lds();      // A-reads done before h writes
    int j = wv*16 + lr;
    #pragma unroll
    for (int ri=0; ri<4; ++ri){
      int row = lk*4 + ri;
      float rr = sigm(acc[0][ri] + sBrz[j]);
      float zz = sigm(acc[1][ri] + sBrz[64+j]);
      float nn = tanh_(acc[2][ri] + sBin[j] + rr*(acc[3][ri] + sBhn[j]));
      float hv = sH[row][j];
      hv = (1.f-zz)*nn + zz*hv;
      sH[row][j] = hv;
      sX[row][8+j] = f2b(hv);
    }
    barrier_lds();
  }

  // ================= initial-state MLP =================
  if (tid < 128){
    #pragma unroll
    for (int cc=0; cc<8; ++cc) sX[orow][ocol*8+cc] = f2b(sH[orow][ocol*8+cc]);
    sX[orow][64+ocol] = f2b(obs[(size_t)(r0+orow)*(T*OBSD) + ocol]);
  }
  barrier_lds();
  {
    s8v a[3], w0[3];
    #pragma unroll
    for (int kk=0;kk<3;++kk){
      a[kk]  = *(const s8v*)&sX[lr][kk*32+lk*8];
      w0[kk] = *(const s8v*)(ws + O_WMLP0 + (wv*16+lr)*96 + kk*32 + lk*8);
    }
    f4v c = {0.f,0.f,0.f,0.f};
    #pragma unroll
    for (int kk=0;kk<3;++kk) c = MFMA(a[kk], w0[kk], c);
    int col = wv*16+lr; float bb = mb0[col];
    #pragma unroll
    for (int ri=0;ri<4;++ri) sXc[lk*4+ri][col] = f2b(tanh_(c[ri]+bb));
  }
  barrier_lds();
  if (wv==0){
    s8v a[2], w1[2];
    #pragma unroll
    for (int kk=0;kk<2;++kk){
      a[kk]  = *(const s8v*)&sXc[lr][kk*32+lk*8];
      w1[kk] = *(const s8v*)(ws + O_WMLP1 + lr*64 + kk*32 + lk*8);
    }
    f4v c = {0.f,0.f,0.f,0.f};
    #pragma unroll
    for (int kk=0;kk<2;++kk) c = MFMA(a[kk], w1[kk], c);
    float bb = mb1[lr];
    #pragma unroll
    for (int ri=0;ri<4;++ri){
      int row = lk*4+ri;
      float s = c[ri]+bb;
      sS[row][lr] = s;
      stt[(size_t)(r0+row)*(T*STD) + lr] = s;
    }
  } else {
    for (int p = tid-64; p < BB*64; p += 192) sH[p/64][p%64] = 0.f;                 // hc = 0
    for (int p = tid-64; p < BB*64; p += 192){ int r=p/64,c=p%64; sX[r][32+c]=0; }  // hc bf16 = 0
  }
  if (tid<128) sBrz[tid] = cbi[tid]+cbh[tid];
  if (tid<64){ sBin[tid]=cbi[128+tid]; sBhn[tid]=cbh[128+tid]; }

  // rollout weight fragments
  s8v wR[4][3];
  #pragma unroll
  for (int g=0; g<4; ++g)
    #pragma unroll
    for (int kk=0; kk<3; ++kk)
      wR[g][kk] = *(const s8v*)(ws + O_WROLL + (g*64 + wv*16 + lr)*96 + kk*32 + lk*8);
  s8v wC0[3];
  #pragma unroll
  for (int kk=0;kk<3;++kk) wC0[kk] = *(const s8v*)(ws + O_WC0 + (wv*16+lr)*96 + kk*32 + lk*8);
  s8v wCl[3][2];
  #pragma unroll
  for (int i=0;i<3;++i)
    #pragma unroll
    for (int kk=0;kk<2;++kk)
      wCl[i][kk] = *(const s8v*)(ws + O_WC + i*4096 + (wv*16+lr)*64 + kk*32 + lk*8);
  s8v wCo[2], wSy;
  if (wv==0){
    #pragma unroll
    for (int kk=0;kk<2;++kk) wCo[kk] = *(const s8v*)(ws + O_WCOUT + lr*64 + kk*32 + lk*8);
    wSy = *(const s8v*)(ws + O_WSYS + lr*32 + lk*8);
  }

  float oxr = 0.f;
  if (tid<128) oxr = obs[(size_t)(r0+orow)*(T*OBSD) + OBSD + ocol];   // obs[:,1]
  barrier_lds();

  // ================= rollout: 199 steps =================
  for (int i=0; i<T-1; ++i){
    // --- A0: pred/err + staging ---
    if (tid < 128){
      float pr = 0.f;
      #pragma unroll
      for (int k=0;k<16;++k) pr += sS[orow][k]*sC[ocol][k];
      oh[(size_t)(r0+orow)*(T*OBSD) + i*OBSD + ocol] = pr;
      float er = oxr - pr;
      unsigned short ob = f2b(oxr), eb = f2b(er);
      sX[orow][16+ocol]=ob; sX[orow][24+ocol]=eb;
      sU[orow][64+ocol]=ob; sU[orow][72+ocol]=eb;
      float s1 = sS[orow][ocol], s2 = sS[orow][8+ocol];
      unsigned short b1v=f2b(s1), b2v=f2b(s2);
      sX[orow][ocol]=b1v;  sX[orow][8+ocol]=b2v;
      sXs[orow][ocol]=b1v; sXs[orow][8+ocol]=b2v;
    }
    barrier_lds();
    if (tid<128 && i+1 < T-1) oxr = obs[(size_t)(r0+orow)*(T*OBSD) + (i+2)*OBSD + ocol];

    // --- GRU GEMM ---
    {
      s8v a[3];
      #pragma unroll
      for (int kk=0;kk<3;++kk) a[kk] = *(const s8v*)&sX[lr][kk*32 + lk*8];
      f4v acc[4];
      #pragma unroll
      for (int g=0; g<4; ++g){
        f4v c = {0.f,0.f,0.f,0.f};
        #pragma unroll
        for (int kk=0;kk<3;++kk) c = MFMA(a[kk], wR[g][kk], c);
        acc[g]=c;
      }
      barrier_lds();
      int j = wv*16 + lr;
      #pragma unroll
      for (int ri=0; ri<4; ++ri){
        int row = lk*4 + ri;
        float rr = sigm(acc[0][ri] + sBrz[j]);
        float zz = sigm(acc[1][ri] + sBrz[64+j]);
        float nn = tanh_(acc[2][ri] + sBin[j] + rr*(acc[3][ri] + sBhn[j]));
        float hv = sH[row][j];
        hv = (1.f-zz)*nn + zz*hv;
        sH[row][j] = hv;
        unsigned short hb = f2b(hv);
        sX[row][32+j] = hb;
        sU[row][j] = hb;
      }
    }
    barrier_lds();

    // --- control L0 ---
    {
      s8v a2[3];
      #pragma unroll
      for (int kk=0;kk<3;++kk) a2[kk] = *(const s8v*)&sU[lr][kk*32+lk*8];
      f4v c = {0.f,0.f,0.f,0.f};
      #pragma unroll
      for (int kk=0;kk<3;++kk) c = MFMA(a2[kk], wC0[kk], c);
      int col = wv*16+lr; float bb = sBc0[col];
      #pragma unroll
      for (int ri=0;ri<4;++ri) sLN[lk*4+ri][col] = fmaxf(c[ri]+bb, 0.f);
    }
    barrier_lds();

    // --- 3 × (LN + layer) ---
    #pragma unroll
    for (int L=0; L<3; ++L){
      if (tid<128){
        float xv[8], sm=0.f, sq=0.f;
        #pragma unroll
        for (int cc=0;cc<8;++cc){ float x=sLN[orow][ocol*8+cc]; xv[cc]=x; sm+=x; sq+=x*x; }
        sm+=__shfl_xor(sm,1); sq+=__shfl_xor(sq,1);
        sm+=__shfl_xor(sm,2); sq+=__shfl_xor(sq,2);
        sm+=__shfl_xor(sm,4); sq+=__shfl_xor(sq,4);
        float mn = sm*0.015625f;
        float vr = sq*0.015625f - mn*mn;
        float scl = rsqrtf(vr + 1e-5f);
        #pragma unroll
        for (int cc=0;cc<8;++cc){ int c2=ocol*8+cc;
          sXc[orow][c2] = f2b((xv[cc]-mn)*scl*sLg[L*64+c2] + sLb[L*64+c2]); }
      }
      barrier_lds();
      s8v a2[2];
      #pragma unroll
      for (int kk=0;kk<2;++kk) a2[kk] = *(const s8v*)&sXc[lr][kk*32+lk*8];
      f4v c = {0.f,0.f,0.f,0.f};
      #pragma unroll
      for (int kk=0;kk<2;++kk) c = MFMA(a2[kk], wCl[L][kk], c);
      int col = wv*16+lr; float bb = sBcl[L*64+col];
      barrier_lds();   // reads of sXc/sLN complete before overwrite
      if (L<2){
        #pragma unroll
        for (int ri=0;ri<4;++ri) sLN[lk*4+ri][col] = fmaxf(c[ri]+bb, 0.f);
      } else {
        #pragma unroll
        for (int ri=0;ri<4;++ri) sXc[lk*4+ri][col] = f2b(fmaxf(c[ri]+bb, 0.f));
      }
      barrier_lds();
    }

    // --- cmd + state update (wave 0) ---
    if (wv==0){
      s8v a2[2];
      #pragma unroll
      for (int kk=0;kk<2;++kk) a2[kk] = *(const s8v*)&sXc[lr][kk*32+lk*8];
      f4v c = {0.f,0.f,0.f,0.f};
      #pragma unroll
      for (int kk=0;kk<2;++kk) c = MFMA(a2[kk], wCo[kk], c);
      if (lr < 4){
        float bb = sBco[lr];
        #pragma unroll
        for (int ri=0;ri<4;++ri){
          int row = lk*4+ri;
          float cv = c[ri]+bb;
          cm[(size_t)(r0+row)*((T-1)*CTD) + i*CTD + lr] = cv;
          sXs[row][16+lr] = f2b(cv);
        }
      }
      s8v as = *(const s8v*)&sXs[lr][lk*8];
      f4v d = {0.f,0.f,0.f,0.f};
      d = MFMA(as, wSy, d);
      #pragma unroll
      for (int ri=0;ri<4;++ri){
        int row = lk*4+ri;
        float ns = sS[row][lr] + d[ri];
        ns = (ns > -100.f && ns < 100.f) ? ns : 0.f;
        sS[row][lr] = ns;
        stt[(size_t)(r0+row)*(T*STD) + (i+1)*STD + lr] = ns;
      }
    }
    barrier_lds();
  }

  // final obs_hat[199]
  if (tid<128){
    float pr = 0.f;
    #pragma unroll
    for (int k=0;k<16;++k) pr += sS[orow][k]*sC[ocol][k];
    oh[(size_t)(r0+orow)*(T*OBSD) + (T-1)*OBSD + ocol] = pr;
  }
}

extern "C" void kernel_launch(void* const* d_in, const int* in_sizes, int n_in,
                              void* d_out, int out_size, void* d_ws, size_t ws_size,
                              hipStream_t stream){
  const float* obs    = (const float*)d_in[0];
  const float* sysA   = (const float*)d_in[1];
  const float* sysB   = (const float*)d_in[2];
  const float* sysC   = (const float*)d_in[3];
  const float* rWi    = (const float*)d_in[4];
  const float* rWh    = (const float*)d_in[5];
  const float* rbi    = (const float*)d_in[6];
  const float* rbh    = (const float*)d_in[7];
  const float* cWi    = (const float*)d_in[8];
  const float* cWh    = (const float*)d_in[9];
  const float* cbi    = (const float*)d_in[10];
  const float* cbh    = (const float*)d_in[11];
  const float* mW0    = (const float*)d_in[12];
  const float* mb0    = (const float*)d_in[13];
  const float* mW1    = (const float*)d_in[14];
  const float* mb1    = (const float*)d_in[15];
  const float* mcW0   = (const float*)d_in[16];
  const float* mcb0   = (const float*)d_in[17];
  const float* lng    = (const float*)d_in[18];
  const float* lnb    = (const float*)d_in[19];
  const float* mcW    = (const float*)d_in[20];
  const float* mcb    = (const float*)d_in[21];
  const float* mcWout = (const float*)d_in[22];
  const float* mcbout = (const float*)d_in[23];
  unsigned short* ws  = (unsigned short*)d_ws;

  prep<<<(WS_TOT+255)/256, 256, 0, stream>>>(rWi,rWh,cWi,cWh,mW0,mW1,mcW0,mcW,mcWout,sysA,sysB,ws);
  fused<<<BT/BB, 256, 0, stream>>>(obs,sysC,rbi,rbh,cbi,cbh,mb0,mb1,mcb0,lng,lnb,mcb,mcbout,ws,(float*)d_out);
}